// Round 1
// 252.106 us; speedup vs baseline: 1.0183x; 1.0183x over previous
//
#include <hip/hip_runtime.h>
#include <stdint.h>

#define SEQ   2048
#define DEMB  512
#define NH    8
#define DH    64
#define BATCH 8
#define M_ROWS (BATCH * SEQ)   // 16384
#define QKLD  1024             // qk buffer row stride (Q|K)
#define QSCALE 0.18033688011112042f   // 0.125 * log2(e)

typedef __attribute__((ext_vector_type(8))) __bf16 bf16x8;
typedef __attribute__((ext_vector_type(4))) __bf16 bf16x4;
typedef __attribute__((ext_vector_type(4))) float  f32x4;
typedef __attribute__((ext_vector_type(8))) uint16_t u16x8;
typedef __attribute__((ext_vector_type(4))) uint32_t u32x4;

__device__ __forceinline__ void gll16(const __bf16* g, __bf16* l) {
    __builtin_amdgcn_global_load_lds(
        (__attribute__((address_space(1))) void*)(__bf16*)g,
        (__attribute__((address_space(3))) void*)l, 16, 0, 0);
}

__device__ __forceinline__ bf16x8 ld8(const __bf16* p) {
    return *(const bf16x8*)p;
}

// pack two fp32 -> bf16 pair, single instruction (RNE)
__device__ __forceinline__ uint32_t cvtpk(float lo, float hi) {
    uint32_t r;
    asm("v_cvt_pk_bf16_f32 %0, %1, %2" : "=v"(r) : "v"(lo), "v"(hi));
    return r;
}

// XOR-swizzled offset into a 64-wide bf16 LDS tile (8-elem chunks)
__device__ __forceinline__ int sw(int row, int chunk) {
    return row * 64 + ((chunk ^ (row & 7)) << 3);
}

// stage 64x64 bf16 tile into swizzled LDS via gll16 (swizzle on global col)
__device__ __forceinline__ void stage_gll_sw(const __bf16* g, int gld,
                                             __bf16* l, int wave, int lane) {
    const int lr = lane >> 3;
    const int scol = ((lane & 7) ^ lr) * 8;
    #pragma unroll
    for (int i = 0; i < 2; i++) {
        const int r0 = i * 32 + wave * 8;
        gll16(g + (size_t)(r0 + lr) * gld + scol, l + r0 * 64);
    }
}

// stage 128x64 bf16 tile via global_load_lds (16B/lane), unswizzled
__device__ __forceinline__ void stage_gll(const __bf16* src, __bf16* dst,
                                          int ld, int wave, int lane) {
    const int srow = lane >> 3, scol = (lane & 7) * 8;
    #pragma unroll
    for (int i = 0; i < 4; i++) {
        const int r0 = (i * 4 + wave) * 8;
        gll16(src + (size_t)(r0 + srow) * ld + scol, dst + r0 * 64);
    }
}

// ---------------------------------------------------------------------------
// fp32->bf16 converts
// ---------------------------------------------------------------------------
#define NXQ (M_ROWS * DEMB / 4)      // 2097152
#define NWQ (3 * DEMB * DEMB / 4)    // 196608
#define NOQ (DEMB * DEMB / 4)        // 65536

__global__ __launch_bounds__(256)
void cvt_all(const float* __restrict__ x, const float* __restrict__ w_in,
             __bf16* __restrict__ xb, __bf16* __restrict__ wb) {
    const int i = blockIdx.x * 256 + threadIdx.x;
    const float4* src;
    bf16x4* dst;
    if (i < NXQ) { src = (const float4*)x + i;         dst = (bf16x4*)xb + i; }
    else if (i < NXQ + NWQ) {
        const int j = i - NXQ;
        src = (const float4*)w_in + j;  dst = (bf16x4*)wb + j;
    } else return;
    const float4 v = *src;
    bf16x4 b;
    b[0] = (__bf16)v.x; b[1] = (__bf16)v.y;
    b[2] = (__bf16)v.z; b[3] = (__bf16)v.w;
    *dst = b;
}

__global__ __launch_bounds__(256)
void cvt_wout(const float* __restrict__ w, __bf16* __restrict__ wb) {
    const int i = blockIdx.x * 256 + threadIdx.x;
    if (i < NOQ) {
        const float4 v = ((const float4*)w)[i];
        bf16x4 b;
        b[0] = (__bf16)v.x; b[1] = (__bf16)v.y;
        b[2] = (__bf16)v.z; b[3] = (__bf16)v.w;
        ((bf16x4*)wb)[i] = b;
    }
}

// ---------------------------------------------------------------------------
// GEMM1: qkv = x_bf16 @ w_in_bf16^T + b_in.  Both operands via gll.
// Q cols pre-scaled by QSCALE.  Q,K -> qk[m][1024].
// V cols -> vt[(b*8+h)*64+d][s] via LDS transpose + coalesced 256B-row stores.
// ---------------------------------------------------------------------------
__global__ __launch_bounds__(256)
void gemm_qkv(const __bf16* __restrict__ A, const __bf16* __restrict__ W,
              const float* __restrict__ bias, __bf16* __restrict__ qk,
              __bf16* __restrict__ vt) {
    constexpr int K = DEMB;
    __shared__ __align__(16) __bf16 SM[128 * 128];   // As | Bs, reused as Tr
    __bf16* As = SM;
    __bf16* Bs = SM + 128 * 64;

    const int tid  = threadIdx.x;
    const int wave = tid >> 6, lane = tid & 63;
    const int quad = lane >> 4, l16 = lane & 15;
    const int m0 = blockIdx.x * 128, n0 = blockIdx.y * 128;
    const int wm = wave & 1, wn = wave >> 1;

    f32x4 acc[4][4] = {};

    for (int k0 = 0; k0 < K; k0 += 64) {
        __syncthreads();
        stage_gll(A + (size_t)m0 * K + k0, As, K, wave, lane);
        stage_gll(W + (size_t)n0 * K + k0, Bs, K, wave, lane);
        __syncthreads();
        #pragma unroll
        for (int ks = 0; ks < 2; ks++) {
            bf16x8 af[4], bf[4];
            #pragma unroll
            for (int t = 0; t < 4; t++) {
                af[t] = ld8(&As[(wm * 64 + t * 16 + l16) * 64 + ks * 32 + quad * 8]);
                bf[t] = ld8(&Bs[(wn * 64 + t * 16 + l16) * 64 + ks * 32 + quad * 8]);
            }
            #pragma unroll
            for (int i = 0; i < 4; i++)
                #pragma unroll
                for (int j = 0; j < 4; j++)
                    acc[i][j] = __builtin_amdgcn_mfma_f32_16x16x32_bf16(
                        af[i], bf[j], acc[i][j], 0, 0, 0);
        }
    }

    if (n0 < QKLD) {
        const float scl = (n0 < DEMB) ? QSCALE : 1.0f;   // pre-scale Q only
        #pragma unroll
        for (int j = 0; j < 4; j++) {
            const int n = n0 + wn * 64 + j * 16 + l16;
            const float bv = bias[n];
            #pragma unroll
            for (int i = 0; i < 4; i++) {
                const int mr = m0 + wm * 64 + i * 16 + quad * 4;
                #pragma unroll
                for (int r = 0; r < 4; r++)
                    qk[(size_t)(mr + r) * QKLD + n] = (__bf16)((acc[i][j][r] + bv) * scl);
            }
        }
    } else {
        // V block: transpose 128(hd) x 128(s) through swizzled LDS
        __syncthreads();                       // all waves done with As/Bs
        const int hd0 = n0 - QKLD;             // 0,128,256,384
        const int bb = m0 >> 11, s0 = m0 & (SEQ - 1);
        #pragma unroll
        for (int j = 0; j < 4; j++) {
            const int n = n0 + wn * 64 + j * 16 + l16;
            const float bv = bias[n];
            const int hdl = wn * 64 + j * 16 + l16;      // local hd row
            #pragma unroll
            for (int i = 0; i < 4; i++) {
                const int sl = wm * 64 + i * 16 + quad * 4;  // local s (4-aligned)
                bf16x4 pk;
                #pragma unroll
                for (int r = 0; r < 4; r++)
                    pk[r] = (__bf16)(acc[i][j][r] + bv);
                const int chunk = sl >> 3;               // 0..15
                const int phys = (((chunk & 7) ^ (hdl & 7)) | (chunk & 8));
                *(bf16x4*)(&SM[hdl * 128 + phys * 8 + (sl & 7)]) = pk;
            }
        }
        __syncthreads();
        // coalesced stores: 16 lanes cover one 256B row
        const int g = tid >> 4, li = tid & 15;
        #pragma unroll
        for (int it = 0; it < 8; it++) {
            const int row = it * 16 + g;
            const int phys = (((li & 7) ^ (row & 7)) | (li & 8));
            bf16x8 v = ld8(&SM[row * 128 + phys * 8]);
            *(bf16x8*)(vt + ((size_t)(bb * DEMB + hd0 + row)) * SEQ + s0 + li * 8) = v;
        }
    }
}

// ---------------------------------------------------------------------------
// Flash attention, S^T formulation, double-buffered gll staging.
// Q pre-scaled so p = exp2(st) via raw v_exp_f32.
// P transpose (C-layout S^T[key][q] -> A-frag P[q][key]) done fully
// in-register via v_permlane32_swap + v_permlane16_swap (no LDS round-trip).
// LDS = 32KB.
// ---------------------------------------------------------------------------
__global__ __launch_bounds__(256)
void attn_flash(const __bf16* __restrict__ qk, const __bf16* __restrict__ vt,
                __bf16* __restrict__ outp) {
    const int qt = blockIdx.x, h = blockIdx.y, b = blockIdx.z;
    const int tid  = threadIdx.x;
    const int wave = tid >> 6, lane = tid & 63;
    const int quad = lane >> 4, l16 = lane & 15;

    __shared__ __align__(16) __bf16 Ks[2][64 * 64];   // 16 KB
    __shared__ __align__(16) __bf16 Vt[2][64 * 64];   // 16 KB

    const size_t brow = (size_t)b * SEQ;
    const int q0 = qt * 128 + wave * 32;
    const __bf16* kbase = qk + brow * QKLD + DEMB + h * DH;
    const __bf16* vbase = vt + ((size_t)(b * DEMB + h * DH)) * SEQ;

    const u16x8 one16 = {0x3F80, 0x3F80, 0x3F80, 0x3F80,
                         0x3F80, 0x3F80, 0x3F80, 0x3F80};
    const bf16x8 ONES = __builtin_bit_cast(bf16x8, one16);

    // Q fragments (B-operand: B[k=quad*8+j][n=l16] = Q[q=l16][d])
    bf16x8 qf[2][2];
    #pragma unroll
    for (int qb = 0; qb < 2; qb++) {
        const __bf16* qp = qk + (brow + q0 + qb * 16 + l16) * QKLD + h * DH + quad * 8;
        qf[qb][0] = ld8(qp);
        qf[qb][1] = ld8(qp + 32);
    }

    f32x4 o[2][4] = {};
    f32x4 osum[2] = {};

    stage_gll_sw(kbase, QKLD, Ks[0], wave, lane);
    stage_gll_sw(vbase, SEQ,  Vt[0], wave, lane);

    for (int t = 0; t < SEQ / 64; t++) {
        __syncthreads();
        if (t + 1 < SEQ / 64) {
            const int nb = (t + 1) & 1;
            stage_gll_sw(kbase + (size_t)(t + 1) * 64 * QKLD, QKLD, Ks[nb], wave, lane);
            stage_gll_sw(vbase + (t + 1) * 64,                SEQ,  Vt[nb], wave, lane);
        }
        const int buf = t & 1;

        // S^T[key][q]: A = K rows, B = Q rows
        f32x4 st[2][4];
        __builtin_amdgcn_s_setprio(1);
        #pragma unroll
        for (int kt = 0; kt < 4; kt++) {
            bf16x8 kf0 = ld8(&Ks[buf][sw(kt * 16 + l16, quad)]);
            bf16x8 kf1 = ld8(&Ks[buf][sw(kt * 16 + l16, 4 + quad)]);
            #pragma unroll
            for (int qb = 0; qb < 2; qb++) {
                f32x4 c = {};
                c = __builtin_amdgcn_mfma_f32_16x16x32_bf16(kf0, qf[qb][0], c, 0, 0, 0);
                c = __builtin_amdgcn_mfma_f32_16x16x32_bf16(kf1, qf[qb][1], c, 0, 0, 0);
                st[qb][kt] = c;
            }
        }
        __builtin_amdgcn_s_setprio(0);

        // exp2 + pack (cvt_pk) + in-register quad transpose via permlane swaps.
        // source: pk[kt][rp] = bf16 pair of keys (16kt + 4*quad + 2rp, +1) at q=l16
        // target: pf[qb][f] = A-frag, dword jp = keys (32f + 8*quad + 2jp, +1)
        bf16x8 pf[2][2];
        #pragma unroll
        for (int qb = 0; qb < 2; qb++) {
            uint32_t pk[4][2];
            #pragma unroll
            for (int kt = 0; kt < 4; kt++) {
                const float p0 = __builtin_amdgcn_exp2f(st[qb][kt][0]);
                const float p1 = __builtin_amdgcn_exp2f(st[qb][kt][1]);
                const float p2 = __builtin_amdgcn_exp2f(st[qb][kt][2]);
                const float p3 = __builtin_amdgcn_exp2f(st[qb][kt][3]);
                pk[kt][0] = cvtpk(p0, p1);
                pk[kt][1] = cvtpk(p2, p3);
            }
            #pragma unroll
            for (int f = 0; f < 2; f++) {
                // rp = 0 chain: swap lane-b5 <-> kt0, then lane-b4 <-> pairidx
                uint32_t a0 = pk[2 * f][0], b0 = pk[2 * f + 1][0];
                asm("v_permlane32_swap_b32 %0, %1" : "+v"(a0), "+v"(b0));
                asm("v_permlane16_swap_b32 %0, %1" : "+v"(a0), "+v"(b0));
                // rp = 1 chain
                uint32_t a1 = pk[2 * f][1], b1 = pk[2 * f + 1][1];
                asm("v_permlane32_swap_b32 %0, %1" : "+v"(a1), "+v"(b1));
                asm("v_permlane16_swap_b32 %0, %1" : "+v"(a1), "+v"(b1));
                // dword order jp0..3 = (s=0,rp=0),(s=0,rp=1),(s=1,rp=0),(s=1,rp=1)
                u32x4 d;
                d[0] = a0; d[1] = a1; d[2] = b0; d[3] = b1;
                pf[qb][f] = __builtin_bit_cast(bf16x8, d);
            }
            osum[qb] = __builtin_amdgcn_mfma_f32_16x16x32_bf16(pf[qb][0], ONES, osum[qb], 0, 0, 0);
            osum[qb] = __builtin_amdgcn_mfma_f32_16x16x32_bf16(pf[qb][1], ONES, osum[qb], 0, 0, 0);
        }

        // PV
        __builtin_amdgcn_s_setprio(1);
        #pragma unroll
        for (int db = 0; db < 4; db++) {
            bf16x8 vf0 = ld8(&Vt[buf][sw(db * 16 + l16, quad)]);
            bf16x8 vf1 = ld8(&Vt[buf][sw(db * 16 + l16, 4 + quad)]);
            #pragma unroll
            for (int qb = 0; qb < 2; qb++) {
                o[qb][db] = __builtin_amdgcn_mfma_f32_16x16x32_bf16(pf[qb][0], vf0, o[qb][db], 0, 0, 0);
                o[qb][db] = __builtin_amdgcn_mfma_f32_16x16x32_bf16(pf[qb][1], vf1, o[qb][db], 0, 0, 0);
            }
        }
        __builtin_amdgcn_s_setprio(0);
    }

    // normalize + store (o, osum share C-layout: row=quad*4+r=q, col=l16=d)
    #pragma unroll
    for (int qb = 0; qb < 2; qb++)
        #pragma unroll
        for (int r = 0; r < 4; r++) {
            const float linv = __builtin_amdgcn_rcpf(osum[qb][r]);
            const int q = q0 + qb * 16 + quad * 4 + r;
            #pragma unroll
            for (int db = 0; db < 4; db++)
                outp[(brow + q) * DEMB + h * DH + db * 16 + l16] =
                    (__bf16)(o[qb][db][r] * linv);
        }
}

// ---------------------------------------------------------------------------
// GEMM2: out = attn @ w_out_bf16^T + b_out  (both via gll, fp32 out)
// ---------------------------------------------------------------------------
__global__ __launch_bounds__(256)
void gemm_out(const __bf16* __restrict__ A, const __bf16* __restrict__ W,
              const float* __restrict__ bias, float* __restrict__ C,
              int N, int K) {
    __shared__ __align__(16) __bf16 As[128 * 64];
    __shared__ __align__(16) __bf16 Bs[128 * 64];

    const int tid  = threadIdx.x;
    const int wave = tid >> 6, lane = tid & 63;
    const int quad = lane >> 4, l16 = lane & 15;
    const int m0 = blockIdx.x * 128, n0 = blockIdx.y * 128;
    const int wm = wave & 1, wn = wave >> 1;

    f32x4 acc[4][4] = {};

    for (int k0 = 0; k0 < K; k0 += 64) {
        __syncthreads();
        stage_gll(A + (size_t)m0 * K + k0, As, K, wave, lane);
        stage_gll(W + (size_t)n0 * K + k0, Bs, K, wave, lane);
        __syncthreads();
        #pragma unroll
        for (int ks = 0; ks < 2; ks++) {
            bf16x8 af[4], bf[4];
            #pragma unroll
            for (int t = 0; t < 4; t++) {
                af[t] = ld8(&As[(wm * 64 + t * 16 + l16) * 64 + ks * 32 + quad * 8]);
                bf[t] = ld8(&Bs[(wn * 64 + t * 16 + l16) * 64 + ks * 32 + quad * 8]);
            }
            #pragma unroll
            for (int i = 0; i < 4; i++)
                #pragma unroll
                for (int j = 0; j < 4; j++)
                    acc[i][j] = __builtin_amdgcn_mfma_f32_16x16x32_bf16(
                        af[i], bf[j], acc[i][j], 0, 0, 0);
        }
    }

    #pragma unroll
    for (int j = 0; j < 4; j++) {
        const int n = n0 + wn * 64 + j * 16 + l16;
        const float bv = bias[n];
        #pragma unroll
        for (int i = 0; i < 4; i++) {
            const int mr = m0 + wm * 64 + i * 16 + quad * 4;
            #pragma unroll
            for (int r = 0; r < 4; r++)
                C[(size_t)(mr + r) * N + n] = acc[i][j][r] + bv;
        }
    }
}

// ---------------------------------------------------------------------------
extern "C" void kernel_launch(void* const* d_in, const int* in_sizes, int n_in,
                              void* d_out, int out_size, void* d_ws, size_t ws_size,
                              hipStream_t stream) {
    const float* x     = (const float*)d_in[0];
    const float* w_in  = (const float*)d_in[1];
    const float* b_in  = (const float*)d_in[2];
    const float* w_out = (const float*)d_in[3];
    const float* b_out = (const float*)d_in[4];

    __bf16* qk   = (__bf16*)d_ws;                    // 16384x1024 = 32 MB
    __bf16* vtb  = qk + (size_t)M_ROWS * QKLD;       // 4096x2048  = 16 MB
    __bf16* xbuf = vtb + (size_t)BATCH * DEMB * SEQ; // 16 MB, ALIASED with aout
    __bf16* aout = xbuf;                             // x_bf16 dead before attn writes
    __bf16* woutb = vtb;                             // vtb dead after attn
    __bf16* winb = (__bf16*)((char*)d_out + 24u * 1024 * 1024);  // 1.5 MB of d_out
    float*  outp = (float*)d_out;

    cvt_all<<<(NXQ + NWQ + 255) / 256, 256, 0, stream>>>(x, w_in, xbuf, winb);
    gemm_qkv<<<dim3(M_ROWS / 128, 12), 256, 0, stream>>>(xbuf, winb, b_in, qk, vtb);
    attn_flash<<<dim3(SEQ / 128, NH, BATCH), 256, 0, stream>>>(qk, vtb, aout);
    cvt_wout<<<NOQ / 256, 256, 0, stream>>>(w_out, woutb);
    gemm_out<<<dim3(M_ROWS / 128, DEMB / 128), 256, 0, stream>>>(
        aout, woutb, b_out, outp, DEMB, DEMB);
}

// Round 3
// 241.983 us; speedup vs baseline: 1.0609x; 1.0418x over previous
//
#include <hip/hip_runtime.h>
#include <stdint.h>

#define SEQ   2048
#define DEMB  512
#define NH    8
#define DH    64
#define BATCH 8
#define M_ROWS (BATCH * SEQ)   // 16384
#define QKLD  1024             // qk buffer row stride (Q|K)
#define QSCALE 0.18033688011112042f   // 0.125 * log2(e)

typedef __attribute__((ext_vector_type(8))) __bf16 bf16x8;
typedef __attribute__((ext_vector_type(4))) __bf16 bf16x4;
typedef __attribute__((ext_vector_type(4))) float  f32x4;
typedef __attribute__((ext_vector_type(8))) uint16_t u16x8;
typedef __attribute__((ext_vector_type(4))) uint32_t u32x4;

__device__ __forceinline__ void gll16(const __bf16* g, __bf16* l) {
    __builtin_amdgcn_global_load_lds(
        (__attribute__((address_space(1))) void*)(__bf16*)g,
        (__attribute__((address_space(3))) void*)l, 16, 0, 0);
}

__device__ __forceinline__ bf16x8 ld8(const __bf16* p) {
    return *(const bf16x8*)p;
}

// pack two fp32 -> bf16 pair via plain casts (compiler emits v_cvt_pk / pack,
// fully visible to the hazard recognizer -- no opaque asm on the data path)
__device__ __forceinline__ uint32_t pkpair(float a, float b) {
    const uint16_t lo = __builtin_bit_cast(uint16_t, (__bf16)a);
    const uint16_t hi = __builtin_bit_cast(uint16_t, (__bf16)b);
    return (uint32_t)lo | ((uint32_t)hi << 16);
}

// XOR-swizzled offset into a 64-wide bf16 LDS tile (8-elem chunks)
__device__ __forceinline__ int sw(int row, int chunk) {
    return row * 64 + ((chunk ^ (row & 7)) << 3);
}

// stage 64x64 bf16 tile into swizzled LDS via gll16 (swizzle on global col)
__device__ __forceinline__ void stage_gll_sw(const __bf16* g, int gld,
                                             __bf16* l, int wave, int lane) {
    const int lr = lane >> 3;
    const int scol = ((lane & 7) ^ lr) * 8;
    #pragma unroll
    for (int i = 0; i < 2; i++) {
        const int r0 = i * 32 + wave * 8;
        gll16(g + (size_t)(r0 + lr) * gld + scol, l + r0 * 64);
    }
}

// stage 128x64 bf16 tile via global_load_lds (16B/lane), unswizzled
__device__ __forceinline__ void stage_gll(const __bf16* src, __bf16* dst,
                                          int ld, int wave, int lane) {
    const int srow = lane >> 3, scol = (lane & 7) * 8;
    #pragma unroll
    for (int i = 0; i < 4; i++) {
        const int r0 = (i * 4 + wave) * 8;
        gll16(src + (size_t)(r0 + srow) * ld + scol, dst + r0 * 64);
    }
}

// ---------------------------------------------------------------------------
// fp32->bf16 converts
// ---------------------------------------------------------------------------
#define NXQ (M_ROWS * DEMB / 4)      // 2097152
#define NWQ (3 * DEMB * DEMB / 4)    // 196608
#define NOQ (DEMB * DEMB / 4)        // 65536

__global__ __launch_bounds__(256)
void cvt_all(const float* __restrict__ x, const float* __restrict__ w_in,
             __bf16* __restrict__ xb, __bf16* __restrict__ wb) {
    const int i = blockIdx.x * 256 + threadIdx.x;
    const float4* src;
    bf16x4* dst;
    if (i < NXQ) { src = (const float4*)x + i;         dst = (bf16x4*)xb + i; }
    else if (i < NXQ + NWQ) {
        const int j = i - NXQ;
        src = (const float4*)w_in + j;  dst = (bf16x4*)wb + j;
    } else return;
    const float4 v = *src;
    bf16x4 b;
    b[0] = (__bf16)v.x; b[1] = (__bf16)v.y;
    b[2] = (__bf16)v.z; b[3] = (__bf16)v.w;
    *dst = b;
}

__global__ __launch_bounds__(256)
void cvt_wout(const float* __restrict__ w, __bf16* __restrict__ wb) {
    const int i = blockIdx.x * 256 + threadIdx.x;
    if (i < NOQ) {
        const float4 v = ((const float4*)w)[i];
        bf16x4 b;
        b[0] = (__bf16)v.x; b[1] = (__bf16)v.y;
        b[2] = (__bf16)v.z; b[3] = (__bf16)v.w;
        ((bf16x4*)wb)[i] = b;
    }
}

// ---------------------------------------------------------------------------
// GEMM1: qkv = x_bf16 @ w_in_bf16^T + b_in.  Both operands via gll.
// Q cols pre-scaled by QSCALE.  Q,K -> qk[m][1024].
// V cols -> vt[(b*8+h)*64+d][s] via LDS transpose + coalesced 256B-row stores.
// ---------------------------------------------------------------------------
__global__ __launch_bounds__(256)
void gemm_qkv(const __bf16* __restrict__ A, const __bf16* __restrict__ W,
              const float* __restrict__ bias, __bf16* __restrict__ qk,
              __bf16* __restrict__ vt) {
    constexpr int K = DEMB;
    __shared__ __align__(16) __bf16 SM[128 * 128];   // As | Bs, reused as Tr
    __bf16* As = SM;
    __bf16* Bs = SM + 128 * 64;

    const int tid  = threadIdx.x;
    const int wave = tid >> 6, lane = tid & 63;
    const int quad = lane >> 4, l16 = lane & 15;
    const int m0 = blockIdx.x * 128, n0 = blockIdx.y * 128;
    const int wm = wave & 1, wn = wave >> 1;

    f32x4 acc[4][4] = {};

    for (int k0 = 0; k0 < K; k0 += 64) {
        __syncthreads();
        stage_gll(A + (size_t)m0 * K + k0, As, K, wave, lane);
        stage_gll(W + (size_t)n0 * K + k0, Bs, K, wave, lane);
        __syncthreads();
        #pragma unroll
        for (int ks = 0; ks < 2; ks++) {
            bf16x8 af[4], bf[4];
            #pragma unroll
            for (int t = 0; t < 4; t++) {
                af[t] = ld8(&As[(wm * 64 + t * 16 + l16) * 64 + ks * 32 + quad * 8]);
                bf[t] = ld8(&Bs[(wn * 64 + t * 16 + l16) * 64 + ks * 32 + quad * 8]);
            }
            #pragma unroll
            for (int i = 0; i < 4; i++)
                #pragma unroll
                for (int j = 0; j < 4; j++)
                    acc[i][j] = __builtin_amdgcn_mfma_f32_16x16x32_bf16(
                        af[i], bf[j], acc[i][j], 0, 0, 0);
        }
    }

    if (n0 < QKLD) {
        const float scl = (n0 < DEMB) ? QSCALE : 1.0f;   // pre-scale Q only
        #pragma unroll
        for (int j = 0; j < 4; j++) {
            const int n = n0 + wn * 64 + j * 16 + l16;
            const float bv = bias[n];
            #pragma unroll
            for (int i = 0; i < 4; i++) {
                const int mr = m0 + wm * 64 + i * 16 + quad * 4;
                #pragma unroll
                for (int r = 0; r < 4; r++)
                    qk[(size_t)(mr + r) * QKLD + n] = (__bf16)((acc[i][j][r] + bv) * scl);
            }
        }
    } else {
        // V block: transpose 128(hd) x 128(s) through swizzled LDS
        __syncthreads();                       // all waves done with As/Bs
        const int hd0 = n0 - QKLD;             // 0,128,256,384
        const int bb = m0 >> 11, s0 = m0 & (SEQ - 1);
        #pragma unroll
        for (int j = 0; j < 4; j++) {
            const int n = n0 + wn * 64 + j * 16 + l16;
            const float bv = bias[n];
            const int hdl = wn * 64 + j * 16 + l16;      // local hd row
            #pragma unroll
            for (int i = 0; i < 4; i++) {
                const int sl = wm * 64 + i * 16 + quad * 4;  // local s (4-aligned)
                bf16x4 pk;
                #pragma unroll
                for (int r = 0; r < 4; r++)
                    pk[r] = (__bf16)(acc[i][j][r] + bv);
                const int chunk = sl >> 3;               // 0..15
                const int phys = (((chunk & 7) ^ (hdl & 7)) | (chunk & 8));
                *(bf16x4*)(&SM[hdl * 128 + phys * 8 + (sl & 7)]) = pk;
            }
        }
        __syncthreads();
        // coalesced stores: 16 lanes cover one 256B row
        const int g = tid >> 4, li = tid & 15;
        #pragma unroll
        for (int it = 0; it < 8; it++) {
            const int row = it * 16 + g;
            const int phys = (((li & 7) ^ (row & 7)) | (li & 8));
            bf16x8 v = ld8(&SM[row * 128 + phys * 8]);
            *(bf16x8*)(vt + ((size_t)(bb * DEMB + hd0 + row)) * SEQ + s0 + li * 8) = v;
        }
    }
}

// ---------------------------------------------------------------------------
// Flash attention, S^T formulation, double-buffered gll staging.
// Q pre-scaled so p = exp2(st) via raw v_exp_f32.
// P transpose fully in-register via __builtin_amdgcn_permlane{32,16}_swap
// (builtins, NOT inline asm: the gfx950 VALU->permlane wait-state hazards are
// only enforced when the hazard recognizer can see the instructions; the
// round-2 asm version miscompiled under register pressure).
// exp2+pack fused into the QK^T loop (fp32 score tile never materialized).
// __launch_bounds__(256,4): target <=128 total VGPRs -> 4 blocks/CU resident.
// LDS = 32KB.
// ---------------------------------------------------------------------------
__global__ __launch_bounds__(256, 4)
void attn_flash(const __bf16* __restrict__ qk, const __bf16* __restrict__ vt,
                __bf16* __restrict__ outp) {
    const int qt = blockIdx.x, h = blockIdx.y, b = blockIdx.z;
    const int tid  = threadIdx.x;
    const int wave = tid >> 6, lane = tid & 63;
    const int quad = lane >> 4, l16 = lane & 15;

    __shared__ __align__(16) __bf16 Ks[2][64 * 64];   // 16 KB
    __shared__ __align__(16) __bf16 Vt[2][64 * 64];   // 16 KB

    const size_t brow = (size_t)b * SEQ;
    const int q0 = qt * 128 + wave * 32;
    const __bf16* kbase = qk + brow * QKLD + DEMB + h * DH;
    const __bf16* vbase = vt + ((size_t)(b * DEMB + h * DH)) * SEQ;

    const u16x8 one16 = {0x3F80, 0x3F80, 0x3F80, 0x3F80,
                         0x3F80, 0x3F80, 0x3F80, 0x3F80};
    const bf16x8 ONES = __builtin_bit_cast(bf16x8, one16);

    // Q fragments (B-operand: B[k=quad*8+j][n=l16] = Q[q=l16][d])
    bf16x8 qf[2][2];
    #pragma unroll
    for (int qb = 0; qb < 2; qb++) {
        const __bf16* qp = qk + (brow + q0 + qb * 16 + l16) * QKLD + h * DH + quad * 8;
        qf[qb][0] = ld8(qp);
        qf[qb][1] = ld8(qp + 32);
    }

    f32x4 o[2][4] = {};
    f32x4 osum[2] = {};

    stage_gll_sw(kbase, QKLD, Ks[0], wave, lane);
    stage_gll_sw(vbase, SEQ,  Vt[0], wave, lane);

    for (int t = 0; t < SEQ / 64; t++) {
        __syncthreads();
        if (t + 1 < SEQ / 64) {
            const int nb = (t + 1) & 1;
            stage_gll_sw(kbase + (size_t)(t + 1) * 64 * QKLD, QKLD, Ks[nb], wave, lane);
            stage_gll_sw(vbase + (t + 1) * 64,                SEQ,  Vt[nb], wave, lane);
        }
        const int buf = t & 1;

        // S^T[key][q] MFMAs with fused exp2+pack.
        // pk[qb][kt][rp] = bf16 pair of keys (16kt + 4*quad + 2rp, +1) at q=l16
        uint32_t pk[2][4][2];
        __builtin_amdgcn_s_setprio(1);
        #pragma unroll
        for (int kt = 0; kt < 4; kt++) {
            bf16x8 kf0 = ld8(&Ks[buf][sw(kt * 16 + l16, quad)]);
            bf16x8 kf1 = ld8(&Ks[buf][sw(kt * 16 + l16, 4 + quad)]);
            #pragma unroll
            for (int qb = 0; qb < 2; qb++) {
                f32x4 c = {};
                c = __builtin_amdgcn_mfma_f32_16x16x32_bf16(kf0, qf[qb][0], c, 0, 0, 0);
                c = __builtin_amdgcn_mfma_f32_16x16x32_bf16(kf1, qf[qb][1], c, 0, 0, 0);
                pk[qb][kt][0] = pkpair(__builtin_amdgcn_exp2f(c[0]),
                                       __builtin_amdgcn_exp2f(c[1]));
                pk[qb][kt][1] = pkpair(__builtin_amdgcn_exp2f(c[2]),
                                       __builtin_amdgcn_exp2f(c[3]));
            }
        }
        __builtin_amdgcn_s_setprio(0);

        // in-register quad transpose via permlane swap builtins
        // target: pf[qb][f] = A-frag, dword jp = keys (32f + 8*quad + 2jp, +1)
        bf16x8 pf[2][2];
        #pragma unroll
        for (int qb = 0; qb < 2; qb++) {
            #pragma unroll
            for (int f = 0; f < 2; f++) {
                uint32_t a0 = pk[qb][2 * f][0], b0 = pk[qb][2 * f + 1][0];
                uint32_t a1 = pk[qb][2 * f][1], b1 = pk[qb][2 * f + 1][1];
                {
                    auto r = __builtin_amdgcn_permlane32_swap(a0, b0, false, false);
                    a0 = r[0]; b0 = r[1];
                }
                {
                    auto r = __builtin_amdgcn_permlane32_swap(a1, b1, false, false);
                    a1 = r[0]; b1 = r[1];
                }
                {
                    auto r = __builtin_amdgcn_permlane16_swap(a0, b0, false, false);
                    a0 = r[0]; b0 = r[1];
                }
                {
                    auto r = __builtin_amdgcn_permlane16_swap(a1, b1, false, false);
                    a1 = r[0]; b1 = r[1];
                }
                u32x4 d;
                d[0] = a0; d[1] = a1; d[2] = b0; d[3] = b1;
                pf[qb][f] = __builtin_bit_cast(bf16x8, d);
            }
            osum[qb] = __builtin_amdgcn_mfma_f32_16x16x32_bf16(pf[qb][0], ONES, osum[qb], 0, 0, 0);
            osum[qb] = __builtin_amdgcn_mfma_f32_16x16x32_bf16(pf[qb][1], ONES, osum[qb], 0, 0, 0);
        }

        // PV
        __builtin_amdgcn_s_setprio(1);
        #pragma unroll
        for (int db = 0; db < 4; db++) {
            bf16x8 vf0 = ld8(&Vt[buf][sw(db * 16 + l16, quad)]);
            bf16x8 vf1 = ld8(&Vt[buf][sw(db * 16 + l16, 4 + quad)]);
            #pragma unroll
            for (int qb = 0; qb < 2; qb++) {
                o[qb][db] = __builtin_amdgcn_mfma_f32_16x16x32_bf16(pf[qb][0], vf0, o[qb][db], 0, 0, 0);
                o[qb][db] = __builtin_amdgcn_mfma_f32_16x16x32_bf16(pf[qb][1], vf1, o[qb][db], 0, 0, 0);
            }
        }
        __builtin_amdgcn_s_setprio(0);
    }

    // normalize + store (o, osum share C-layout: row=quad*4+r=q, col=l16=d)
    #pragma unroll
    for (int qb = 0; qb < 2; qb++)
        #pragma unroll
        for (int r = 0; r < 4; r++) {
            const float linv = __builtin_amdgcn_rcpf(osum[qb][r]);
            const int q = q0 + qb * 16 + quad * 4 + r;
            #pragma unroll
            for (int db = 0; db < 4; db++)
                outp[(brow + q) * DEMB + h * DH + db * 16 + l16] =
                    (__bf16)(o[qb][db][r] * linv);
        }
}

// ---------------------------------------------------------------------------
// GEMM2: out = attn @ w_out_bf16^T + b_out  (both via gll, fp32 out)
// ---------------------------------------------------------------------------
__global__ __launch_bounds__(256)
void gemm_out(const __bf16* __restrict__ A, const __bf16* __restrict__ W,
              const float* __restrict__ bias, float* __restrict__ C,
              int N, int K) {
    __shared__ __align__(16) __bf16 As[128 * 64];
    __shared__ __align__(16) __bf16 Bs[128 * 64];

    const int tid  = threadIdx.x;
    const int wave = tid >> 6, lane = tid & 63;
    const int quad = lane >> 4, l16 = lane & 15;
    const int m0 = blockIdx.x * 128, n0 = blockIdx.y * 128;
    const int wm = wave & 1, wn = wave >> 1;

    f32x4 acc[4][4] = {};

    for (int k0 = 0; k0 < K; k0 += 64) {
        __syncthreads();
        stage_gll(A + (size_t)m0 * K + k0, As, K, wave, lane);
        stage_gll(W + (size_t)n0 * K + k0, Bs, K, wave, lane);
        __syncthreads();
        #pragma unroll
        for (int ks = 0; ks < 2; ks++) {
            bf16x8 af[4], bf[4];
            #pragma unroll
            for (int t = 0; t < 4; t++) {
                af[t] = ld8(&As[(wm * 64 + t * 16 + l16) * 64 + ks * 32 + quad * 8]);
                bf[t] = ld8(&Bs[(wn * 64 + t * 16 + l16) * 64 + ks * 32 + quad * 8]);
            }
            #pragma unroll
            for (int i = 0; i < 4; i++)
                #pragma unroll
                for (int j = 0; j < 4; j++)
                    acc[i][j] = __builtin_amdgcn_mfma_f32_16x16x32_bf16(
                        af[i], bf[j], acc[i][j], 0, 0, 0);
        }
    }

    #pragma unroll
    for (int j = 0; j < 4; j++) {
        const int n = n0 + wn * 64 + j * 16 + l16;
        const float bv = bias[n];
        #pragma unroll
        for (int i = 0; i < 4; i++) {
            const int mr = m0 + wm * 64 + i * 16 + quad * 4;
            #pragma unroll
            for (int r = 0; r < 4; r++)
                C[(size_t)(mr + r) * N + n] = acc[i][j][r] + bv;
        }
    }
}

// ---------------------------------------------------------------------------
extern "C" void kernel_launch(void* const* d_in, const int* in_sizes, int n_in,
                              void* d_out, int out_size, void* d_ws, size_t ws_size,
                              hipStream_t stream) {
    const float* x     = (const float*)d_in[0];
    const float* w_in  = (const float*)d_in[1];
    const float* b_in  = (const float*)d_in[2];
    const float* w_out = (const float*)d_in[3];
    const float* b_out = (const float*)d_in[4];

    __bf16* qk   = (__bf16*)d_ws;                    // 16384x1024 = 32 MB
    __bf16* vtb  = qk + (size_t)M_ROWS * QKLD;       // 4096x2048  = 16 MB
    __bf16* xbuf = vtb + (size_t)BATCH * DEMB * SEQ; // 16 MB, ALIASED with aout
    __bf16* aout = xbuf;                             // x_bf16 dead before attn writes
    __bf16* woutb = vtb;                             // vtb dead after attn
    __bf16* winb = (__bf16*)((char*)d_out + 24u * 1024 * 1024);  // 1.5 MB of d_out
    float*  outp = (float*)d_out;

    cvt_all<<<(NXQ + NWQ + 255) / 256, 256, 0, stream>>>(x, w_in, xbuf, winb);
    gemm_qkv<<<dim3(M_ROWS / 128, 12), 256, 0, stream>>>(xbuf, winb, b_in, qk, vtb);
    attn_flash<<<dim3(SEQ / 128, NH, BATCH), 256, 0, stream>>>(qk, vtb, aout);
    cvt_wout<<<NOQ / 256, 256, 0, stream>>>(w_out, woutb);
    gemm_out<<<dim3(M_ROWS / 128, DEMB / 128), 256, 0, stream>>>(
        aout, woutb, b_out, outp, DEMB, DEMB);
}

// Round 4
// 233.449 us; speedup vs baseline: 1.0996x; 1.0366x over previous
//
#include <hip/hip_runtime.h>
#include <stdint.h>

#define SEQ   2048
#define DEMB  512
#define NH    8
#define DH    64
#define BATCH 8
#define M_ROWS (BATCH * SEQ)   // 16384
#define QKLD  1024             // qk buffer row stride (Q|K)
#define QSCALE 0.18033688011112042f   // 0.125 * log2(e)

typedef __attribute__((ext_vector_type(8))) __bf16 bf16x8;
typedef __attribute__((ext_vector_type(4))) __bf16 bf16x4;
typedef __attribute__((ext_vector_type(4))) float  f32x4;
typedef __attribute__((ext_vector_type(8))) uint16_t u16x8;
typedef __attribute__((ext_vector_type(4))) uint32_t u32x4;

__device__ __forceinline__ void gll16(const __bf16* g, __bf16* l) {
    __builtin_amdgcn_global_load_lds(
        (__attribute__((address_space(1))) void*)(__bf16*)g,
        (__attribute__((address_space(3))) void*)l, 16, 0, 0);
}

__device__ __forceinline__ bf16x8 ld8(const __bf16* p) {
    return *(const bf16x8*)p;
}

// pack two fp32 -> bf16 pair via plain casts (hazard-recognizer-visible)
__device__ __forceinline__ uint32_t pkpair(float a, float b) {
    const uint16_t lo = __builtin_bit_cast(uint16_t, (__bf16)a);
    const uint16_t hi = __builtin_bit_cast(uint16_t, (__bf16)b);
    return (uint32_t)lo | ((uint32_t)hi << 16);
}

// XOR-swizzled offset into a 64-wide bf16 LDS tile (8-elem chunks)
__device__ __forceinline__ int sw(int row, int chunk) {
    return row * 64 + ((chunk ^ (row & 7)) << 3);
}

// stage 64x64 bf16 tile into swizzled LDS via gll16 (swizzle on global col)
__device__ __forceinline__ void stage_gll_sw(const __bf16* g, int gld,
                                             __bf16* l, int wave, int lane) {
    const int lr = lane >> 3;
    const int scol = ((lane & 7) ^ lr) * 8;
    #pragma unroll
    for (int i = 0; i < 2; i++) {
        const int r0 = i * 32 + wave * 8;
        gll16(g + (size_t)(r0 + lr) * gld + scol, l + r0 * 64);
    }
}

// stage 128x64 bf16 tile via global_load_lds (16B/lane), unswizzled
__device__ __forceinline__ void stage_gll(const __bf16* src, __bf16* dst,
                                          int ld, int wave, int lane) {
    const int srow = lane >> 3, scol = (lane & 7) * 8;
    #pragma unroll
    for (int i = 0; i < 4; i++) {
        const int r0 = (i * 4 + wave) * 8;
        gll16(src + (size_t)(r0 + srow) * ld + scol, dst + r0 * 64);
    }
}

// ---------------------------------------------------------------------------
// fp32->bf16 converts
// ---------------------------------------------------------------------------
#define NXQ (M_ROWS * DEMB / 4)      // 2097152
#define NWQ (3 * DEMB * DEMB / 4)    // 196608
#define NOQ (DEMB * DEMB / 4)        // 65536

__global__ __launch_bounds__(256)
void cvt_all(const float* __restrict__ x, const float* __restrict__ w_in,
             __bf16* __restrict__ xb, __bf16* __restrict__ wb) {
    const int i = blockIdx.x * 256 + threadIdx.x;
    const float4* src;
    bf16x4* dst;
    if (i < NXQ) { src = (const float4*)x + i;         dst = (bf16x4*)xb + i; }
    else if (i < NXQ + NWQ) {
        const int j = i - NXQ;
        src = (const float4*)w_in + j;  dst = (bf16x4*)wb + j;
    } else return;
    const float4 v = *src;
    bf16x4 b;
    b[0] = (__bf16)v.x; b[1] = (__bf16)v.y;
    b[2] = (__bf16)v.z; b[3] = (__bf16)v.w;
    *dst = b;
}

__global__ __launch_bounds__(256)
void cvt_wout(const float* __restrict__ w, __bf16* __restrict__ wb) {
    const int i = blockIdx.x * 256 + threadIdx.x;
    if (i < NOQ) {
        const float4 v = ((const float4*)w)[i];
        bf16x4 b;
        b[0] = (__bf16)v.x; b[1] = (__bf16)v.y;
        b[2] = (__bf16)v.z; b[3] = (__bf16)v.w;
        ((bf16x4*)wb)[i] = b;
    }
}

// ---------------------------------------------------------------------------
// GEMM1: qkv = x_bf16 @ w_in_bf16^T + b_in.  Both operands via gll.
// Q cols pre-scaled by QSCALE.  Q,K -> qk[m][1024].
// Q/K blocks: MFMA operands SWAPPED (acc holds n on quad/reg axis) so the
//   epilogue writes bf16x4 (4 consecutive n) to swizzled LDS, then does
//   fully-coalesced bf16x8 row stores (replaces 64 scalar 2B global stores).
// V cols -> vt[(b*8+h)*64+d][s] via LDS transpose + coalesced 256B-row stores.
// ---------------------------------------------------------------------------
__global__ __launch_bounds__(256)
void gemm_qkv(const __bf16* __restrict__ A, const __bf16* __restrict__ W,
              const float* __restrict__ bias, __bf16* __restrict__ qk,
              __bf16* __restrict__ vt) {
    constexpr int K = DEMB;
    __shared__ __align__(16) __bf16 SM[128 * 128];   // As | Bs, reused for C
    __bf16* As = SM;
    __bf16* Bs = SM + 128 * 64;

    const int tid  = threadIdx.x;
    const int wave = tid >> 6, lane = tid & 63;
    const int quad = lane >> 4, l16 = lane & 15;
    const int m0 = blockIdx.x * 128, n0 = blockIdx.y * 128;
    const int wm = wave & 1, wn = wave >> 1;
    const bool qkblk = (n0 < QKLD);

    // qkblk: acc[j][i], output row-dim = n (quad*4+r), col-dim = m (l16)
    // else : acc[i][j], output row-dim = m (quad*4+r), col-dim = n (l16)
    f32x4 acc[4][4] = {};

    for (int k0 = 0; k0 < K; k0 += 64) {
        __syncthreads();
        stage_gll(A + (size_t)m0 * K + k0, As, K, wave, lane);
        stage_gll(W + (size_t)n0 * K + k0, Bs, K, wave, lane);
        __syncthreads();
        #pragma unroll
        for (int ks = 0; ks < 2; ks++) {
            bf16x8 af[4], bf[4];
            #pragma unroll
            for (int t = 0; t < 4; t++) {
                af[t] = ld8(&As[(wm * 64 + t * 16 + l16) * 64 + ks * 32 + quad * 8]);
                bf[t] = ld8(&Bs[(wn * 64 + t * 16 + l16) * 64 + ks * 32 + quad * 8]);
            }
            if (qkblk) {
                #pragma unroll
                for (int j = 0; j < 4; j++)
                    #pragma unroll
                    for (int i = 0; i < 4; i++)
                        acc[j][i] = __builtin_amdgcn_mfma_f32_16x16x32_bf16(
                            bf[j], af[i], acc[j][i], 0, 0, 0);
            } else {
                #pragma unroll
                for (int i = 0; i < 4; i++)
                    #pragma unroll
                    for (int j = 0; j < 4; j++)
                        acc[i][j] = __builtin_amdgcn_mfma_f32_16x16x32_bf16(
                            af[i], bf[j], acc[i][j], 0, 0, 0);
            }
        }
    }

    __syncthreads();   // all waves done reading As/Bs before SM reuse

    if (qkblk) {
        const float scl = (n0 < DEMB) ? QSCALE : 1.0f;   // pre-scale Q only
        // stage C[m][n] into swizzled SM: bf16x4 = 4 consecutive n per write
        #pragma unroll
        for (int j = 0; j < 4; j++) {
            const int nl = wn * 64 + j * 16 + quad * 4;
            const float4 bv4 = *(const float4*)&bias[n0 + nl];
            const int chunk = nl >> 3;                   // wn*8 + j*2 + (quad>>1)
            #pragma unroll
            for (int i = 0; i < 4; i++) {
                const int ml = wm * 64 + i * 16 + l16;
                bf16x4 pk;
                pk[0] = (__bf16)((acc[j][i][0] + bv4.x) * scl);
                pk[1] = (__bf16)((acc[j][i][1] + bv4.y) * scl);
                pk[2] = (__bf16)((acc[j][i][2] + bv4.z) * scl);
                pk[3] = (__bf16)((acc[j][i][3] + bv4.w) * scl);
                const int phys = ((chunk & 7) ^ (ml & 7)) | (chunk & 8);
                *(bf16x4*)(&SM[ml * 128 + phys * 8 + (nl & 7)]) = pk;
            }
        }
        __syncthreads();
        // coalesced stores: 16 lanes cover one 256B row of qk
        const int g = tid >> 4, li = tid & 15;
        #pragma unroll
        for (int it = 0; it < 8; it++) {
            const int row = it * 16 + g;
            const int phys = ((li & 7) ^ (row & 7)) | (li & 8);
            bf16x8 v = ld8(&SM[row * 128 + phys * 8]);
            *(bf16x8*)(qk + (size_t)(m0 + row) * QKLD + n0 + li * 8) = v;
        }
    } else {
        // V block: transpose 128(hd) x 128(s) through swizzled LDS
        const int hd0 = n0 - QKLD;             // 0,128,256,384
        const int bb = m0 >> 11, s0 = m0 & (SEQ - 1);
        #pragma unroll
        for (int j = 0; j < 4; j++) {
            const int n = n0 + wn * 64 + j * 16 + l16;
            const float bv = bias[n];
            const int hdl = wn * 64 + j * 16 + l16;      // local hd row
            #pragma unroll
            for (int i = 0; i < 4; i++) {
                const int sl = wm * 64 + i * 16 + quad * 4;  // local s (4-aligned)
                bf16x4 pk;
                #pragma unroll
                for (int r = 0; r < 4; r++)
                    pk[r] = (__bf16)(acc[i][j][r] + bv);
                const int chunk = sl >> 3;               // 0..15
                const int phys = (((chunk & 7) ^ (hdl & 7)) | (chunk & 8));
                *(bf16x4*)(&SM[hdl * 128 + phys * 8 + (sl & 7)]) = pk;
            }
        }
        __syncthreads();
        // coalesced stores: 16 lanes cover one 256B row
        const int g = tid >> 4, li = tid & 15;
        #pragma unroll
        for (int it = 0; it < 8; it++) {
            const int row = it * 16 + g;
            const int phys = (((li & 7) ^ (row & 7)) | (li & 8));
            bf16x8 v = ld8(&SM[row * 128 + phys * 8]);
            *(bf16x8*)(vt + ((size_t)(bb * DEMB + hd0 + row)) * SEQ + s0 + li * 8) = v;
        }
    }
}

// ---------------------------------------------------------------------------
// Flash attention, S^T formulation, double-buffered gll staging.
// (unchanged from round 3: permlane-swap builtins, fused exp2+pack,
//  __launch_bounds__(256,4), LDS=32KB)
// ---------------------------------------------------------------------------
__global__ __launch_bounds__(256, 4)
void attn_flash(const __bf16* __restrict__ qk, const __bf16* __restrict__ vt,
                __bf16* __restrict__ outp) {
    const int qt = blockIdx.x, h = blockIdx.y, b = blockIdx.z;
    const int tid  = threadIdx.x;
    const int wave = tid >> 6, lane = tid & 63;
    const int quad = lane >> 4, l16 = lane & 15;

    __shared__ __align__(16) __bf16 Ks[2][64 * 64];   // 16 KB
    __shared__ __align__(16) __bf16 Vt[2][64 * 64];   // 16 KB

    const size_t brow = (size_t)b * SEQ;
    const int q0 = qt * 128 + wave * 32;
    const __bf16* kbase = qk + brow * QKLD + DEMB + h * DH;
    const __bf16* vbase = vt + ((size_t)(b * DEMB + h * DH)) * SEQ;

    const u16x8 one16 = {0x3F80, 0x3F80, 0x3F80, 0x3F80,
                         0x3F80, 0x3F80, 0x3F80, 0x3F80};
    const bf16x8 ONES = __builtin_bit_cast(bf16x8, one16);

    // Q fragments (B-operand: B[k=quad*8+j][n=l16] = Q[q=l16][d])
    bf16x8 qf[2][2];
    #pragma unroll
    for (int qb = 0; qb < 2; qb++) {
        const __bf16* qp = qk + (brow + q0 + qb * 16 + l16) * QKLD + h * DH + quad * 8;
        qf[qb][0] = ld8(qp);
        qf[qb][1] = ld8(qp + 32);
    }

    f32x4 o[2][4] = {};
    f32x4 osum[2] = {};

    stage_gll_sw(kbase, QKLD, Ks[0], wave, lane);
    stage_gll_sw(vbase, SEQ,  Vt[0], wave, lane);

    for (int t = 0; t < SEQ / 64; t++) {
        __syncthreads();
        if (t + 1 < SEQ / 64) {
            const int nb = (t + 1) & 1;
            stage_gll_sw(kbase + (size_t)(t + 1) * 64 * QKLD, QKLD, Ks[nb], wave, lane);
            stage_gll_sw(vbase + (t + 1) * 64,                SEQ,  Vt[nb], wave, lane);
        }
        const int buf = t & 1;

        // S^T[key][q] MFMAs with fused exp2+pack.
        // pk[qb][kt][rp] = bf16 pair of keys (16kt + 4*quad + 2rp, +1) at q=l16
        uint32_t pk[2][4][2];
        __builtin_amdgcn_s_setprio(1);
        #pragma unroll
        for (int kt = 0; kt < 4; kt++) {
            bf16x8 kf0 = ld8(&Ks[buf][sw(kt * 16 + l16, quad)]);
            bf16x8 kf1 = ld8(&Ks[buf][sw(kt * 16 + l16, 4 + quad)]);
            #pragma unroll
            for (int qb = 0; qb < 2; qb++) {
                f32x4 c = {};
                c = __builtin_amdgcn_mfma_f32_16x16x32_bf16(kf0, qf[qb][0], c, 0, 0, 0);
                c = __builtin_amdgcn_mfma_f32_16x16x32_bf16(kf1, qf[qb][1], c, 0, 0, 0);
                pk[qb][kt][0] = pkpair(__builtin_amdgcn_exp2f(c[0]),
                                       __builtin_amdgcn_exp2f(c[1]));
                pk[qb][kt][1] = pkpair(__builtin_amdgcn_exp2f(c[2]),
                                       __builtin_amdgcn_exp2f(c[3]));
            }
        }
        __builtin_amdgcn_s_setprio(0);

        // in-register quad transpose via permlane swap builtins
        // target: pf[qb][f] = A-frag, dword jp = keys (32f + 8*quad + 2jp, +1)
        bf16x8 pf[2][2];
        #pragma unroll
        for (int qb = 0; qb < 2; qb++) {
            #pragma unroll
            for (int f = 0; f < 2; f++) {
                uint32_t a0 = pk[qb][2 * f][0], b0 = pk[qb][2 * f + 1][0];
                uint32_t a1 = pk[qb][2 * f][1], b1 = pk[qb][2 * f + 1][1];
                {
                    auto r = __builtin_amdgcn_permlane32_swap(a0, b0, false, false);
                    a0 = r[0]; b0 = r[1];
                }
                {
                    auto r = __builtin_amdgcn_permlane32_swap(a1, b1, false, false);
                    a1 = r[0]; b1 = r[1];
                }
                {
                    auto r = __builtin_amdgcn_permlane16_swap(a0, b0, false, false);
                    a0 = r[0]; b0 = r[1];
                }
                {
                    auto r = __builtin_amdgcn_permlane16_swap(a1, b1, false, false);
                    a1 = r[0]; b1 = r[1];
                }
                u32x4 d;
                d[0] = a0; d[1] = a1; d[2] = b0; d[3] = b1;
                pf[qb][f] = __builtin_bit_cast(bf16x8, d);
            }
            osum[qb] = __builtin_amdgcn_mfma_f32_16x16x32_bf16(pf[qb][0], ONES, osum[qb], 0, 0, 0);
            osum[qb] = __builtin_amdgcn_mfma_f32_16x16x32_bf16(pf[qb][1], ONES, osum[qb], 0, 0, 0);
        }

        // PV
        __builtin_amdgcn_s_setprio(1);
        #pragma unroll
        for (int db = 0; db < 4; db++) {
            bf16x8 vf0 = ld8(&Vt[buf][sw(db * 16 + l16, quad)]);
            bf16x8 vf1 = ld8(&Vt[buf][sw(db * 16 + l16, 4 + quad)]);
            #pragma unroll
            for (int qb = 0; qb < 2; qb++) {
                o[qb][db] = __builtin_amdgcn_mfma_f32_16x16x32_bf16(pf[qb][0], vf0, o[qb][db], 0, 0, 0);
                o[qb][db] = __builtin_amdgcn_mfma_f32_16x16x32_bf16(pf[qb][1], vf1, o[qb][db], 0, 0, 0);
            }
        }
        __builtin_amdgcn_s_setprio(0);
    }

    // normalize + store (o, osum share C-layout: row=quad*4+r=q, col=l16=d)
    #pragma unroll
    for (int qb = 0; qb < 2; qb++)
        #pragma unroll
        for (int r = 0; r < 4; r++) {
            const float linv = __builtin_amdgcn_rcpf(osum[qb][r]);
            const int q = q0 + qb * 16 + quad * 4 + r;
            #pragma unroll
            for (int db = 0; db < 4; db++)
                outp[(brow + q) * DEMB + h * DH + db * 16 + l16] =
                    (__bf16)(o[qb][db][r] * linv);
        }
}

// ---------------------------------------------------------------------------
// GEMM2: out = attn @ w_out_bf16^T + b_out  (both via gll, fp32 out).
// MFMA operands SWAPPED so acc holds 4 consecutive n per fragment; epilogue
// stages fp32 through LDS (two 64-row passes over the 32KB As|Bs space) and
// does fully-coalesced float4 stores (replaces 64 scalar 4B global stores).
// ---------------------------------------------------------------------------
__global__ __launch_bounds__(256)
void gemm_out(const __bf16* __restrict__ A, const __bf16* __restrict__ W,
              const float* __restrict__ bias, float* __restrict__ C,
              int N, int K) {
    __shared__ __align__(16) __bf16 SMO[2 * 128 * 64];   // As|Bs, reused fp32
    __bf16* As = SMO;
    __bf16* Bs = SMO + 128 * 64;

    const int tid  = threadIdx.x;
    const int wave = tid >> 6, lane = tid & 63;
    const int quad = lane >> 4, l16 = lane & 15;
    const int m0 = blockIdx.x * 128, n0 = blockIdx.y * 128;
    const int wm = wave & 1, wn = wave >> 1;

    // acc[j][i]: output row-dim = n (quad*4+r), col-dim = m (l16)
    f32x4 acc[4][4] = {};

    for (int k0 = 0; k0 < K; k0 += 64) {
        __syncthreads();
        stage_gll(A + (size_t)m0 * K + k0, As, K, wave, lane);
        stage_gll(W + (size_t)n0 * K + k0, Bs, K, wave, lane);
        __syncthreads();
        #pragma unroll
        for (int ks = 0; ks < 2; ks++) {
            bf16x8 af[4], bf[4];
            #pragma unroll
            for (int t = 0; t < 4; t++) {
                af[t] = ld8(&As[(wm * 64 + t * 16 + l16) * 64 + ks * 32 + quad * 8]);
                bf[t] = ld8(&Bs[(wn * 64 + t * 16 + l16) * 64 + ks * 32 + quad * 8]);
            }
            #pragma unroll
            for (int j = 0; j < 4; j++)
                #pragma unroll
                for (int i = 0; i < 4; i++)
                    acc[j][i] = __builtin_amdgcn_mfma_f32_16x16x32_bf16(
                        bf[j], af[i], acc[j][i], 0, 0, 0);
        }
    }

    __syncthreads();   // all waves done reading As/Bs
    float* SMf = (float*)SMO;     // 64 rows x 128 cols fp32 per pass = 32KB

    #pragma unroll
    for (int p = 0; p < 2; p++) {
        if (p) __syncthreads();   // pass-0 reads done before pass-1 writes
        if (wm == p) {
            #pragma unroll
            for (int j = 0; j < 4; j++) {
                const int nl = wn * 64 + j * 16 + quad * 4;
                const float4 bv4 = *(const float4*)&bias[n0 + nl];
                const int chunkf = nl >> 2;              // 0..31 (16B chunks)
                #pragma unroll
                for (int i = 0; i < 4; i++) {
                    const int ml = i * 16 + l16;         // local row 0..63
                    const int physf = ((chunkf & 7) ^ (ml & 7)) | (chunkf & 24);
                    float4 v;
                    v.x = acc[j][i][0] + bv4.x;
                    v.y = acc[j][i][1] + bv4.y;
                    v.z = acc[j][i][2] + bv4.z;
                    v.w = acc[j][i][3] + bv4.w;
                    *(float4*)(&SMf[ml * 128 + physf * 4]) = v;
                }
            }
        }
        __syncthreads();
        // coalesced stores: 32 lanes cover one 512B row
        const int g2 = tid >> 5, li2 = tid & 31;
        #pragma unroll
        for (int it = 0; it < 8; it++) {
            const int row = it * 8 + g2;
            const int physf = ((li2 & 7) ^ (row & 7)) | (li2 & 24);
            float4 v = *(const float4*)&SMf[row * 128 + physf * 4];
            *(float4*)(&C[(size_t)(m0 + p * 64 + row) * N + n0 + li2 * 4]) = v;
        }
    }
}

// ---------------------------------------------------------------------------
extern "C" void kernel_launch(void* const* d_in, const int* in_sizes, int n_in,
                              void* d_out, int out_size, void* d_ws, size_t ws_size,
                              hipStream_t stream) {
    const float* x     = (const float*)d_in[0];
    const float* w_in  = (const float*)d_in[1];
    const float* b_in  = (const float*)d_in[2];
    const float* w_out = (const float*)d_in[3];
    const float* b_out = (const float*)d_in[4];

    __bf16* qk   = (__bf16*)d_ws;                    // 16384x1024 = 32 MB
    __bf16* vtb  = qk + (size_t)M_ROWS * QKLD;       // 4096x2048  = 16 MB
    __bf16* xbuf = vtb + (size_t)BATCH * DEMB * SEQ; // 16 MB, ALIASED with aout
    __bf16* aout = xbuf;                             // x_bf16 dead before attn writes
    __bf16* woutb = vtb;                             // vtb dead after attn
    __bf16* winb = (__bf16*)((char*)d_out + 24u * 1024 * 1024);  // 1.5 MB of d_out
    float*  outp = (float*)d_out;

    cvt_all<<<(NXQ + NWQ + 255) / 256, 256, 0, stream>>>(x, w_in, xbuf, winb);
    gemm_qkv<<<dim3(M_ROWS / 128, 12), 256, 0, stream>>>(xbuf, winb, b_in, qk, vtb);
    attn_flash<<<dim3(SEQ / 128, NH, BATCH), 256, 0, stream>>>(qk, vtb, aout);
    cvt_wout<<<NOQ / 256, 256, 0, stream>>>(w_out, woutb);
    gemm_out<<<dim3(M_ROWS / 128, DEMB / 128), 256, 0, stream>>>(
        aout, woutb, b_out, outp, DEMB, DEMB);
}

// Round 5
// 230.040 us; speedup vs baseline: 1.1159x; 1.0148x over previous
//
#include <hip/hip_runtime.h>
#include <stdint.h>

#define SEQ   2048
#define DEMB  512
#define NH    8
#define DH    64
#define BATCH 8
#define M_ROWS (BATCH * SEQ)   // 16384
#define QKLD  1024             // qk buffer row stride (Q|K)
#define QSCALE 0.18033688011112042f   // 0.125 * log2(e)

typedef __attribute__((ext_vector_type(8))) __bf16 bf16x8;
typedef __attribute__((ext_vector_type(4))) __bf16 bf16x4;
typedef __attribute__((ext_vector_type(4))) float  f32x4;
typedef __attribute__((ext_vector_type(8))) uint16_t u16x8;
typedef __attribute__((ext_vector_type(4))) uint32_t u32x4;

__device__ __forceinline__ void gll16(const __bf16* g, __bf16* l) {
    __builtin_amdgcn_global_load_lds(
        (__attribute__((address_space(1))) void*)(__bf16*)g,
        (__attribute__((address_space(3))) void*)l, 16, 0, 0);
}

__device__ __forceinline__ bf16x8 ld8(const __bf16* p) {
    return *(const bf16x8*)p;
}

// pack two fp32 -> bf16 pair via plain casts (hazard-recognizer-visible)
__device__ __forceinline__ uint32_t pkpair(float a, float b) {
    const uint16_t lo = __builtin_bit_cast(uint16_t, (__bf16)a);
    const uint16_t hi = __builtin_bit_cast(uint16_t, (__bf16)b);
    return (uint32_t)lo | ((uint32_t)hi << 16);
}

// XOR-swizzled offset into a 64-wide bf16 LDS tile (8-elem chunks)
__device__ __forceinline__ int sw(int row, int chunk) {
    return row * 64 + ((chunk ^ (row & 7)) << 3);
}

// stage 64x64 bf16 tile into swizzled LDS via gll16 (swizzle on global col)
__device__ __forceinline__ void stage_gll_sw(const __bf16* g, int gld,
                                             __bf16* l, int wave, int lane) {
    const int lr = lane >> 3;
    const int scol = ((lane & 7) ^ lr) * 8;
    #pragma unroll
    for (int i = 0; i < 2; i++) {
        const int r0 = i * 32 + wave * 8;
        gll16(g + (size_t)(r0 + lr) * gld + scol, l + r0 * 64);
    }
}

// stage 128x64 bf16 tile via global_load_lds (16B/lane), unswizzled
__device__ __forceinline__ void stage_gll(const __bf16* src, __bf16* dst,
                                          int ld, int wave, int lane) {
    const int srow = lane >> 3, scol = (lane & 7) * 8;
    #pragma unroll
    for (int i = 0; i < 4; i++) {
        const int r0 = (i * 4 + wave) * 8;
        gll16(src + (size_t)(r0 + srow) * ld + scol, dst + r0 * 64);
    }
}

// ---------------------------------------------------------------------------
// fp32->bf16 converts
// ---------------------------------------------------------------------------
#define NXQ (M_ROWS * DEMB / 4)      // 2097152
#define NWQ (3 * DEMB * DEMB / 4)    // 196608
#define NOQ (DEMB * DEMB / 4)        // 65536

__global__ __launch_bounds__(256)
void cvt_all(const float* __restrict__ x, const float* __restrict__ w_in,
             __bf16* __restrict__ xb, __bf16* __restrict__ wb) {
    const int i = blockIdx.x * 256 + threadIdx.x;
    const float4* src;
    bf16x4* dst;
    if (i < NXQ) { src = (const float4*)x + i;         dst = (bf16x4*)xb + i; }
    else if (i < NXQ + NWQ) {
        const int j = i - NXQ;
        src = (const float4*)w_in + j;  dst = (bf16x4*)wb + j;
    } else return;
    const float4 v = *src;
    bf16x4 b;
    b[0] = (__bf16)v.x; b[1] = (__bf16)v.y;
    b[2] = (__bf16)v.z; b[3] = (__bf16)v.w;
    *dst = b;
}

__global__ __launch_bounds__(256)
void cvt_wout(const float* __restrict__ w, __bf16* __restrict__ wb) {
    const int i = blockIdx.x * 256 + threadIdx.x;
    if (i < NOQ) {
        const float4 v = ((const float4*)w)[i];
        bf16x4 b;
        b[0] = (__bf16)v.x; b[1] = (__bf16)v.y;
        b[2] = (__bf16)v.z; b[3] = (__bf16)v.w;
        ((bf16x4*)wb)[i] = b;
    }
}

// ---------------------------------------------------------------------------
// GEMM1: qkv = x_bf16 @ w_in_bf16^T + b_in.  Both operands via gll.
// Q cols pre-scaled by QSCALE.  Q,K -> qk[m][1024].
// Q/K blocks: MFMA operands SWAPPED (acc holds n on quad/reg axis) so the
//   epilogue writes bf16x4 (4 consecutive n) to swizzled LDS, then does
//   fully-coalesced bf16x8 row stores (replaces 64 scalar 2B global stores).
// V cols -> vt[(b*8+h)*64+d][s] via LDS transpose + coalesced 256B-row stores.
// ---------------------------------------------------------------------------
__global__ __launch_bounds__(256)
void gemm_qkv(const __bf16* __restrict__ A, const __bf16* __restrict__ W,
              const float* __restrict__ bias, __bf16* __restrict__ qk,
              __bf16* __restrict__ vt) {
    constexpr int K = DEMB;
    __shared__ __align__(16) __bf16 SM[128 * 128];   // As | Bs, reused for C
    __bf16* As = SM;
    __bf16* Bs = SM + 128 * 64;

    const int tid  = threadIdx.x;
    const int wave = tid >> 6, lane = tid & 63;
    const int quad = lane >> 4, l16 = lane & 15;
    const int m0 = blockIdx.x * 128, n0 = blockIdx.y * 128;
    const int wm = wave & 1, wn = wave >> 1;
    const bool qkblk = (n0 < QKLD);

    // qkblk: acc[j][i], output row-dim = n (quad*4+r), col-dim = m (l16)
    // else : acc[i][j], output row-dim = m (quad*4+r), col-dim = n (l16)
    f32x4 acc[4][4] = {};

    for (int k0 = 0; k0 < K; k0 += 64) {
        __syncthreads();
        stage_gll(A + (size_t)m0 * K + k0, As, K, wave, lane);
        stage_gll(W + (size_t)n0 * K + k0, Bs, K, wave, lane);
        __syncthreads();
        #pragma unroll
        for (int ks = 0; ks < 2; ks++) {
            bf16x8 af[4], bf[4];
            #pragma unroll
            for (int t = 0; t < 4; t++) {
                af[t] = ld8(&As[(wm * 64 + t * 16 + l16) * 64 + ks * 32 + quad * 8]);
                bf[t] = ld8(&Bs[(wn * 64 + t * 16 + l16) * 64 + ks * 32 + quad * 8]);
            }
            if (qkblk) {
                #pragma unroll
                for (int j = 0; j < 4; j++)
                    #pragma unroll
                    for (int i = 0; i < 4; i++)
                        acc[j][i] = __builtin_amdgcn_mfma_f32_16x16x32_bf16(
                            bf[j], af[i], acc[j][i], 0, 0, 0);
            } else {
                #pragma unroll
                for (int i = 0; i < 4; i++)
                    #pragma unroll
                    for (int j = 0; j < 4; j++)
                        acc[i][j] = __builtin_amdgcn_mfma_f32_16x16x32_bf16(
                            af[i], bf[j], acc[i][j], 0, 0, 0);
            }
        }
    }

    __syncthreads();   // all waves done reading As/Bs before SM reuse

    if (qkblk) {
        const float scl = (n0 < DEMB) ? QSCALE : 1.0f;   // pre-scale Q only
        // stage C[m][n] into swizzled SM: bf16x4 = 4 consecutive n per write
        #pragma unroll
        for (int j = 0; j < 4; j++) {
            const int nl = wn * 64 + j * 16 + quad * 4;
            const float4 bv4 = *(const float4*)&bias[n0 + nl];
            const int chunk = nl >> 3;                   // wn*8 + j*2 + (quad>>1)
            #pragma unroll
            for (int i = 0; i < 4; i++) {
                const int ml = wm * 64 + i * 16 + l16;
                bf16x4 pk;
                pk[0] = (__bf16)((acc[j][i][0] + bv4.x) * scl);
                pk[1] = (__bf16)((acc[j][i][1] + bv4.y) * scl);
                pk[2] = (__bf16)((acc[j][i][2] + bv4.z) * scl);
                pk[3] = (__bf16)((acc[j][i][3] + bv4.w) * scl);
                const int phys = ((chunk & 7) ^ (ml & 7)) | (chunk & 8);
                *(bf16x4*)(&SM[ml * 128 + phys * 8 + (nl & 7)]) = pk;
            }
        }
        __syncthreads();
        // coalesced stores: 16 lanes cover one 256B row of qk
        const int g = tid >> 4, li = tid & 15;
        #pragma unroll
        for (int it = 0; it < 8; it++) {
            const int row = it * 16 + g;
            const int phys = ((li & 7) ^ (row & 7)) | (li & 8);
            bf16x8 v = ld8(&SM[row * 128 + phys * 8]);
            *(bf16x8*)(qk + (size_t)(m0 + row) * QKLD + n0 + li * 8) = v;
        }
    } else {
        // V block: transpose 128(hd) x 128(s) through swizzled LDS
        const int hd0 = n0 - QKLD;             // 0,128,256,384
        const int bb = m0 >> 11, s0 = m0 & (SEQ - 1);
        #pragma unroll
        for (int j = 0; j < 4; j++) {
            const int n = n0 + wn * 64 + j * 16 + l16;
            const float bv = bias[n];
            const int hdl = wn * 64 + j * 16 + l16;      // local hd row
            #pragma unroll
            for (int i = 0; i < 4; i++) {
                const int sl = wm * 64 + i * 16 + quad * 4;  // local s (4-aligned)
                bf16x4 pk;
                #pragma unroll
                for (int r = 0; r < 4; r++)
                    pk[r] = (__bf16)(acc[i][j][r] + bv);
                const int chunk = sl >> 3;               // 0..15
                const int phys = (((chunk & 7) ^ (hdl & 7)) | (chunk & 8));
                *(bf16x4*)(&SM[hdl * 128 + phys * 8 + (sl & 7)]) = pk;
            }
        }
        __syncthreads();
        // coalesced stores: 16 lanes cover one 256B row
        const int g = tid >> 4, li = tid & 15;
        #pragma unroll
        for (int it = 0; it < 8; it++) {
            const int row = it * 16 + g;
            const int phys = (((li & 7) ^ (row & 7)) | (li & 8));
            bf16x8 v = ld8(&SM[row * 128 + phys * 8]);
            *(bf16x8*)(vt + ((size_t)(bb * DEMB + hd0 + row)) * SEQ + s0 + li * 8) = v;
        }
    }
}

// ---------------------------------------------------------------------------
// Flash attention, S^T formulation, SOFTWARE-PIPELINED across k-tiles:
// iteration t overlaps softmax(t) [VALU/trans] with QK^T(t+1) [MFMA] and
// PV(t) [MFMA] in the same wave.  Score tile st[] carried across iterations.
// Buffering: K staged 2-ahead into Ks[t&1] (its QK read finished last iter),
// V staged 1-ahead as before; one barrier per iteration.
// permlane-swap builtins for the P quad-transpose; fused exp2+pack.
// __launch_bounds__(256,3): st[] costs +32 VGPR; cap ~170 avoids spill.
// LDS = 32KB.
// ---------------------------------------------------------------------------
__global__ __launch_bounds__(256, 3)
void attn_flash(const __bf16* __restrict__ qk, const __bf16* __restrict__ vt,
                __bf16* __restrict__ outp) {
    const int qt = blockIdx.x, h = blockIdx.y, b = blockIdx.z;
    const int tid  = threadIdx.x;
    const int wave = tid >> 6, lane = tid & 63;
    const int quad = lane >> 4, l16 = lane & 15;

    __shared__ __align__(16) __bf16 Ks[2][64 * 64];   // 16 KB
    __shared__ __align__(16) __bf16 Vt[2][64 * 64];   // 16 KB

    const size_t brow = (size_t)b * SEQ;
    const int q0 = qt * 128 + wave * 32;
    const __bf16* kbase = qk + brow * QKLD + DEMB + h * DH;
    const __bf16* vbase = vt + ((size_t)(b * DEMB + h * DH)) * SEQ;

    const u16x8 one16 = {0x3F80, 0x3F80, 0x3F80, 0x3F80,
                         0x3F80, 0x3F80, 0x3F80, 0x3F80};
    const bf16x8 ONES = __builtin_bit_cast(bf16x8, one16);

    // Q fragments (B-operand: B[k=quad*8+j][n=l16] = Q[q=l16][d])
    bf16x8 qf[2][2];
    #pragma unroll
    for (int qb = 0; qb < 2; qb++) {
        const __bf16* qp = qk + (brow + q0 + qb * 16 + l16) * QKLD + h * DH + quad * 8;
        qf[qb][0] = ld8(qp);
        qf[qb][1] = ld8(qp + 32);
    }

    f32x4 o[2][4] = {};
    f32x4 osum[2] = {};
    f32x4 st[2][4];          // score tile, carried across iterations
    bf16x8 pf[2][2];         // P fragments of the current softmax'd tile

    // QK^T for tile tt: st[qb][kt] = S^T[key][q] (A = K rows, B = Q rows)
    auto do_qk = [&](int tt) {
        const int bufq = tt & 1;
        #pragma unroll
        for (int kt = 0; kt < 4; kt++) {
            bf16x8 kf0 = ld8(&Ks[bufq][sw(kt * 16 + l16, quad)]);
            bf16x8 kf1 = ld8(&Ks[bufq][sw(kt * 16 + l16, 4 + quad)]);
            #pragma unroll
            for (int qb = 0; qb < 2; qb++) {
                f32x4 c = {};
                c = __builtin_amdgcn_mfma_f32_16x16x32_bf16(kf0, qf[qb][0], c, 0, 0, 0);
                c = __builtin_amdgcn_mfma_f32_16x16x32_bf16(kf1, qf[qb][1], c, 0, 0, 0);
                st[qb][kt] = c;
            }
        }
    };

    // exp2 + pack + in-register quad transpose (permlane swaps) + rowsum
    auto do_softmax = [&]() {
        #pragma unroll
        for (int qb = 0; qb < 2; qb++) {
            uint32_t pk[4][2];
            #pragma unroll
            for (int kt = 0; kt < 4; kt++) {
                pk[kt][0] = pkpair(__builtin_amdgcn_exp2f(st[qb][kt][0]),
                                   __builtin_amdgcn_exp2f(st[qb][kt][1]));
                pk[kt][1] = pkpair(__builtin_amdgcn_exp2f(st[qb][kt][2]),
                                   __builtin_amdgcn_exp2f(st[qb][kt][3]));
            }
            #pragma unroll
            for (int f = 0; f < 2; f++) {
                uint32_t a0 = pk[2 * f][0], b0 = pk[2 * f + 1][0];
                uint32_t a1 = pk[2 * f][1], b1 = pk[2 * f + 1][1];
                {
                    auto r = __builtin_amdgcn_permlane32_swap(a0, b0, false, false);
                    a0 = r[0]; b0 = r[1];
                }
                {
                    auto r = __builtin_amdgcn_permlane32_swap(a1, b1, false, false);
                    a1 = r[0]; b1 = r[1];
                }
                {
                    auto r = __builtin_amdgcn_permlane16_swap(a0, b0, false, false);
                    a0 = r[0]; b0 = r[1];
                }
                {
                    auto r = __builtin_amdgcn_permlane16_swap(a1, b1, false, false);
                    a1 = r[0]; b1 = r[1];
                }
                u32x4 d;
                d[0] = a0; d[1] = a1; d[2] = b0; d[3] = b1;
                pf[qb][f] = __builtin_bit_cast(bf16x8, d);
            }
            osum[qb] = __builtin_amdgcn_mfma_f32_16x16x32_bf16(pf[qb][0], ONES, osum[qb], 0, 0, 0);
            osum[qb] = __builtin_amdgcn_mfma_f32_16x16x32_bf16(pf[qb][1], ONES, osum[qb], 0, 0, 0);
        }
    };

    auto do_pv = [&](int tt) {
        const int bufv = tt & 1;
        #pragma unroll
        for (int db = 0; db < 4; db++) {
            bf16x8 vf0 = ld8(&Vt[bufv][sw(db * 16 + l16, quad)]);
            bf16x8 vf1 = ld8(&Vt[bufv][sw(db * 16 + l16, 4 + quad)]);
            #pragma unroll
            for (int qb = 0; qb < 2; qb++) {
                o[qb][db] = __builtin_amdgcn_mfma_f32_16x16x32_bf16(pf[qb][0], vf0, o[qb][db], 0, 0, 0);
                o[qb][db] = __builtin_amdgcn_mfma_f32_16x16x32_bf16(pf[qb][1], vf1, o[qb][db], 0, 0, 0);
            }
        }
    };

    constexpr int NT = SEQ / 64;

    // prologue: K0, V0, K1 staged; QK(0) computed
    stage_gll_sw(kbase,                      QKLD, Ks[0], wave, lane);
    stage_gll_sw(vbase,                      SEQ,  Vt[0], wave, lane);
    stage_gll_sw(kbase + (size_t)64 * QKLD,  QKLD, Ks[1], wave, lane);
    __syncthreads();
    do_qk(0);

    for (int t = 0; t < NT - 1; ++t) {
        __syncthreads();
        // stage K[t+2] into Ks[t&1] (QK(t) read of it finished last iter);
        // stage V[t+1] into Vt[(t+1)&1] (PV(t-1) read finished last iter)
        if (t + 2 < NT)
            stage_gll_sw(kbase + (size_t)(t + 2) * 64 * QKLD, QKLD, Ks[t & 1], wave, lane);
        stage_gll_sw(vbase + (t + 1) * 64, SEQ, Vt[(t + 1) & 1], wave, lane);

        do_softmax();                    // VALU/trans on st(t) -> pf
        __builtin_amdgcn_s_setprio(1);
        do_qk(t + 1);                    // MFMA, independent of softmax(t)
        do_pv(t);                        // MFMA, consumes pf
        __builtin_amdgcn_s_setprio(0);
    }

    // tail: softmax + PV of the last tile
    __syncthreads();
    do_softmax();
    do_pv(NT - 1);

    // normalize + store (o, osum share C-layout: row=quad*4+r=q, col=l16=d)
    #pragma unroll
    for (int qb = 0; qb < 2; qb++)
        #pragma unroll
        for (int r = 0; r < 4; r++) {
            const float linv = __builtin_amdgcn_rcpf(osum[qb][r]);
            const int q = q0 + qb * 16 + quad * 4 + r;
            #pragma unroll
            for (int db = 0; db < 4; db++)
                outp[(brow + q) * DEMB + h * DH + db * 16 + l16] =
                    (__bf16)(o[qb][db][r] * linv);
        }
}

// ---------------------------------------------------------------------------
// GEMM2: out = attn @ w_out_bf16^T + b_out  (both via gll, fp32 out).
// MFMA operands SWAPPED so acc holds 4 consecutive n per fragment; epilogue
// stages fp32 through LDS (two 64-row passes over the 32KB As|Bs space) and
// does fully-coalesced float4 stores (replaces 64 scalar 4B global stores).
// ---------------------------------------------------------------------------
__global__ __launch_bounds__(256)
void gemm_out(const __bf16* __restrict__ A, const __bf16* __restrict__ W,
              const float* __restrict__ bias, float* __restrict__ C,
              int N, int K) {
    __shared__ __align__(16) __bf16 SMO[2 * 128 * 64];   // As|Bs, reused fp32
    __bf16* As = SMO;
    __bf16* Bs = SMO + 128 * 64;

    const int tid  = threadIdx.x;
    const int wave = tid >> 6, lane = tid & 63;
    const int quad = lane >> 4, l16 = lane & 15;
    const int m0 = blockIdx.x * 128, n0 = blockIdx.y * 128;
    const int wm = wave & 1, wn = wave >> 1;

    // acc[j][i]: output row-dim = n (quad*4+r), col-dim = m (l16)
    f32x4 acc[4][4] = {};

    for (int k0 = 0; k0 < K; k0 += 64) {
        __syncthreads();
        stage_gll(A + (size_t)m0 * K + k0, As, K, wave, lane);
        stage_gll(W + (size_t)n0 * K + k0, Bs, K, wave, lane);
        __syncthreads();
        #pragma unroll
        for (int ks = 0; ks < 2; ks++) {
            bf16x8 af[4], bf[4];
            #pragma unroll
            for (int t = 0; t < 4; t++) {
                af[t] = ld8(&As[(wm * 64 + t * 16 + l16) * 64 + ks * 32 + quad * 8]);
                bf[t] = ld8(&Bs[(wn * 64 + t * 16 + l16) * 64 + ks * 32 + quad * 8]);
            }
            #pragma unroll
            for (int j = 0; j < 4; j++)
                #pragma unroll
                for (int i = 0; i < 4; i++)
                    acc[j][i] = __builtin_amdgcn_mfma_f32_16x16x32_bf16(
                        bf[j], af[i], acc[j][i], 0, 0, 0);
        }
    }

    __syncthreads();   // all waves done reading As/Bs
    float* SMf = (float*)SMO;     // 64 rows x 128 cols fp32 per pass = 32KB

    #pragma unroll
    for (int p = 0; p < 2; p++) {
        if (p) __syncthreads();   // pass-0 reads done before pass-1 writes
        if (wm == p) {
            #pragma unroll
            for (int j = 0; j < 4; j++) {
                const int nl = wn * 64 + j * 16 + quad * 4;
                const float4 bv4 = *(const float4*)&bias[n0 + nl];
                const int chunkf = nl >> 2;              // 0..31 (16B chunks)
                #pragma unroll
                for (int i = 0; i < 4; i++) {
                    const int ml = i * 16 + l16;         // local row 0..63
                    const int physf = ((chunkf & 7) ^ (ml & 7)) | (chunkf & 24);
                    float4 v;
                    v.x = acc[j][i][0] + bv4.x;
                    v.y = acc[j][i][1] + bv4.y;
                    v.z = acc[j][i][2] + bv4.z;
                    v.w = acc[j][i][3] + bv4.w;
                    *(float4*)(&SMf[ml * 128 + physf * 4]) = v;
                }
            }
        }
        __syncthreads();
        // coalesced stores: 32 lanes cover one 512B row
        const int g2 = tid >> 5, li2 = tid & 31;
        #pragma unroll
        for (int it = 0; it < 8; it++) {
            const int row = it * 8 + g2;
            const int physf = ((li2 & 7) ^ (row & 7)) | (li2 & 24);
            float4 v = *(const float4*)&SMf[row * 128 + physf * 4];
            *(float4*)(&C[(size_t)(m0 + p * 64 + row) * N + n0 + li2 * 4]) = v;
        }
    }
}

// ---------------------------------------------------------------------------
extern "C" void kernel_launch(void* const* d_in, const int* in_sizes, int n_in,
                              void* d_out, int out_size, void* d_ws, size_t ws_size,
                              hipStream_t stream) {
    const float* x     = (const float*)d_in[0];
    const float* w_in  = (const float*)d_in[1];
    const float* b_in  = (const float*)d_in[2];
    const float* w_out = (const float*)d_in[3];
    const float* b_out = (const float*)d_in[4];

    __bf16* qk   = (__bf16*)d_ws;                    // 16384x1024 = 32 MB
    __bf16* vtb  = qk + (size_t)M_ROWS * QKLD;       // 4096x2048  = 16 MB
    __bf16* xbuf = vtb + (size_t)BATCH * DEMB * SEQ; // 16 MB, ALIASED with aout
    __bf16* aout = xbuf;                             // x_bf16 dead before attn writes
    __bf16* woutb = vtb;                             // vtb dead after attn
    __bf16* winb = (__bf16*)((char*)d_out + 24u * 1024 * 1024);  // 1.5 MB of d_out
    float*  outp = (float*)d_out;

    cvt_all<<<(NXQ + NWQ + 255) / 256, 256, 0, stream>>>(x, w_in, xbuf, winb);
    gemm_qkv<<<dim3(M_ROWS / 128, 12), 256, 0, stream>>>(xbuf, winb, b_in, qk, vtb);
    attn_flash<<<dim3(SEQ / 128, NH, BATCH), 256, 0, stream>>>(qk, vtb, aout);
    cvt_wout<<<NOQ / 256, 256, 0, stream>>>(w_out, woutb);
    gemm_out<<<dim3(M_ROWS / 128, DEMB / 128), 256, 0, stream>>>(
        aout, woutb, b_out, outp, DEMB, DEMB);
}